// Round 4
// baseline (349.304 us; speedup 1.0000x reference)
//
#include <hip/hip_runtime.h>
#include <hip/hip_bf16.h>

#define CIN 512
#define COUT 512
#define BATCH 16
#define NP 3844          // 62*62 output positions
#define OW 62

#define W_MUL_DENSE 0.044194173824159216f
#define W_MUL_CONV  0.014731391274719736f

using short8  = __attribute__((ext_vector_type(8))) short;
using floatx4 = __attribute__((ext_vector_type(4))) float;
using uintx4  = __attribute__((ext_vector_type(4))) unsigned int;

__device__ __forceinline__ unsigned short f2bfu(float f) {
    unsigned u = __builtin_bit_cast(unsigned, f);
    u += 0x7FFFu + ((u >> 16) & 1u);   // round-to-nearest-even
    return (unsigned short)(u >> 16);
}

__device__ __forceinline__ void gload_lds16(const void* g, void* l) {
    __builtin_amdgcn_global_load_lds(
        (const __attribute__((address_space(1))) void*)g,
        (__attribute__((address_space(3))) void*)l, 16, 0, 0);
}

// ---------------- prep kernels ----------------

__global__ void emc_style_kernel(const float* __restrict__ y, const float* __restrict__ dw,
                                 const float* __restrict__ db, float* __restrict__ s) {
    int idx = blockIdx.x * 256 + threadIdx.x;       // 16*512
    int b = idx >> 9, c = idx & 511;
    const float4* yb = (const float4*)(y + b * 512);
    const float4* wc = (const float4*)(dw + c * 512);
    float acc = 0.f;
#pragma unroll 4
    for (int l = 0; l < 128; ++l) {
        float4 a = yb[l], w4 = wc[l];
        acc += a.x * w4.x + a.y * w4.y + a.z * w4.z + a.w * w4.w;
    }
    s[idx] = acc * W_MUL_DENSE + db[c];
}

__global__ void emc_wsq_kernel(const float* __restrict__ w, float* __restrict__ wsq) {
    int idx = blockIdx.x * 256 + threadIdx.x;       // 512*512
    const float* p = w + (size_t)idx * 9;
    float a = 0.f;
#pragma unroll
    for (int j = 0; j < 9; ++j) a += p[j] * p[j];
    wsq[idx] = a;
}

__global__ void emc_demod_kernel(const float* __restrict__ s, const float* __restrict__ wsq,
                                 float* __restrict__ d) {
    int idx = blockIdx.x * 256 + threadIdx.x;       // 16*512
    int b = idx >> 9, o = idx & 511;
    const float4* sb = (const float4*)(s + b * 512);
    const float4* wo = (const float4*)(wsq + o * 512);
    float acc = 0.f;
#pragma unroll 4
    for (int l = 0; l < 128; ++l) {
        float4 a = sb[l], c = wo[l];
        acc += a.x * a.x * c.x + a.y * a.y * c.y + a.z * a.z * c.z + a.w * a.w * c.w;
    }
    d[idx] = rsqrtf(W_MUL_CONV * W_MUL_CONV * acc + 1e-8f);
}

// wb[(o*9+kpos)*512 + i] = bf16(w[(o*512+i)*9 + kpos])  (linear, K-contig in i per kpos)
__global__ void emc_wrepack_kernel(const float* __restrict__ w, unsigned short* __restrict__ wb) {
    int idx = blockIdx.x * 256 + threadIdx.x;       // 512*9*512
    int i = idx & 511;
    int r = idx >> 9;
    int kpos = r % 9;
    int o = r / 9;
    wb[idx] = f2bfu(w[(size_t)(o * 512 + i) * 9 + kpos]);
}

// ---------------- main conv kernel ----------------
// Tile: BM=256 (o) x strip of 2 output rows (124 p, padded 128).
// B (x-halo): [4 rows][64 cols][32 i] bf16 in 80B granules, staged once per i-tile,
//   reused by all 9 kpos via shifted reads.
// A (weights): 256x32 bf16 per (kpos,i-tile), TRIPLE-buffered via global_load_lds
//   width-16 issued TWO phases ahead; raw s_barrier + counted s_waitcnt vmcnt(4)
//   keeps the newest DMA batch in flight across barriers (T3/T4). T5 setprio
//   around the MFMA cluster. Buffer rotation: phase k reads smA[k%3], DMA targets
//   smA[(k+2)%3]; since 9 % 3 == 0, kpos%3 is compile-time under the unroll.

__global__ __launch_bounds__(256, 2) void emc_conv_kernel(
    const float* __restrict__ x, const unsigned short* __restrict__ wb,
    const float* __restrict__ sv, const float* __restrict__ dv,
    float* __restrict__ out) {

    __shared__ __align__(16) unsigned short smA[3][256 * 32];   // 3 x 16 KB
    __shared__ __align__(16) unsigned short smB[260 * 40];      // 20.8 KB
    __shared__ float s_s[512];
    __shared__ float s_d[256];

    // bijective XCD swizzle (gridDim = 992, 992 % 8 == 0)
    int orig = blockIdx.x;
    int cpx = gridDim.x >> 3;
    int bid = (orig & 7) * cpx + (orig >> 3);

    int b = bid / 62;               // 62 blocks per batch = 2 o-tiles * 31 strips
    int t = bid - b * 62;
    int ot = t & 1;
    int strip = t >> 1;
    int oB = ot * 256;
    int r0 = strip * 2;

    int tid = threadIdx.x;
    int lane = tid & 63;
    int wid = tid >> 6;

    s_s[tid]       = sv[b * 512 + tid];
    s_s[tid + 256] = sv[b * 512 + 256 + tid];
    s_d[tid]       = dv[b * 512 + oB + tid];

    // ---- B staging ids: thread owns (input row sr, col sc) ----
    int sc = tid & 63;
    int sr = tid >> 6;
    const float* xrow = x + (size_t)b * (512 * 4096) + (r0 + sr) * 64 + sc;
    unsigned short* bg = smB + (sr * 64 + sc) * 40;

    // ---- A DMA ids: wave wid covers rows [wid*64, wid*64+64), 4 instrs ----
    const unsigned short* asrc[4];
    int adst[4];
#pragma unroll
    for (int j = 0; j < 4; ++j) {
        int row = wid * 64 + j * 16 + (lane >> 2);
        asrc[j] = wb + (size_t)(oB + row) * 4608 + (((lane & 3) ^ ((row >> 1) & 3)) << 3);
        adst[j] = (wid * 64 + j * 16) * 32;
    }

    // ---- compute ids ----
    int frc = lane & 15, q = lane >> 4;
    int wr = wid >> 1, wc = wid & 1;    // wr: o-half (128 rows), wc: output row in strip
    int aidx[8], bidx[4];
#pragma unroll
    for (int m = 0; m < 8; ++m) {
        int row = wr * 128 + m * 16 + frc;
        aidx[m] = row * 32 + ((q ^ ((row >> 1) & 3)) << 3);
    }
#pragma unroll
    for (int n = 0; n < 4; ++n) bidx[n] = (wc * 64 + n * 16 + frc) * 40 + q * 8;

    floatx4 acc[8][4];
#pragma unroll
    for (int m = 0; m < 8; ++m)
#pragma unroll
        for (int n = 0; n < 4; ++n) acc[m][n] = floatx4{0.f, 0.f, 0.f, 0.f};

    unsigned held[16];

    auto ISSUE_A = [&](int kN, int iN, int bufsel) {
        int off = kN * 512 + iN * 32;
#pragma unroll
        for (int j = 0; j < 4; ++j)
            gload_lds16(asrc[j] + off, &smA[bufsel][adst[j]]);
    };

    auto STAGE_SLICE = [&](int itgt, int sl) {   // 4 i-values of i-tile itgt
        const float* xp = xrow + ((size_t)itgt * 32 + sl * 4) * 4096;
        int i0 = itgt * 32 + sl * 4;
        float v0 = xp[0]        * s_s[i0];
        float v1 = xp[4096]     * s_s[i0 + 1];
        float v2 = xp[2 * 4096] * s_s[i0 + 2];
        float v3 = xp[3 * 4096] * s_s[i0 + 3];
        held[2 * sl]     = (unsigned)f2bfu(v0) | ((unsigned)f2bfu(v1) << 16);
        held[2 * sl + 1] = (unsigned)f2bfu(v2) | ((unsigned)f2bfu(v3) << 16);
    };

    auto WRITE_B = [&]() {
        *(uintx4*)(bg)      = uintx4{held[0],  held[1],  held[2],  held[3]};
        *(uintx4*)(bg + 8)  = uintx4{held[4],  held[5],  held[6],  held[7]};
        *(uintx4*)(bg + 16) = uintx4{held[8],  held[9],  held[10], held[11]};
        *(uintx4*)(bg + 24) = uintx4{held[12], held[13], held[14], held[15]};
    };

    auto COMPUTE = [&](int kpos, int bufsel) {
        int kh = kpos / 3, kw = kpos - kh * 3;
        int bo = (kh * 64 + kw) * 40;
        const unsigned short* A = smA[bufsel];
        short8 bfr[4];
#pragma unroll
        for (int n = 0; n < 4; ++n) bfr[n] = *(const short8*)(smB + bidx[n] + bo);
        __builtin_amdgcn_s_setprio(1);
#pragma unroll
        for (int mh = 0; mh < 2; ++mh) {
            short8 af[4];
#pragma unroll
            for (int mm = 0; mm < 4; ++mm) af[mm] = *(const short8*)(A + aidx[mh * 4 + mm]);
#pragma unroll
            for (int mm = 0; mm < 4; ++mm)
#pragma unroll
                for (int n = 0; n < 4; ++n)
                    acc[mh * 4 + mm][n] = __builtin_amdgcn_mfma_f32_16x16x32_bf16(
                        af[mm], bfr[n], acc[mh * 4 + mm][n], 0, 0, 0);
        }
        __builtin_amdgcn_s_setprio(0);
    };

    __syncthreads();   // s_s / s_d ready

    // ---- prologue: DMA phases 0,1; stage + write full B(i-tile 0) ----
    ISSUE_A(0, 0, 0);
    ISSUE_A(1, 0, 1);
#pragma unroll
    for (int sl = 0; sl < 8; ++sl) STAGE_SLICE(0, sl);
    WRITE_B();
    asm volatile("s_waitcnt vmcnt(4) lgkmcnt(0)" ::: "memory");
    __builtin_amdgcn_s_barrier();

    // ---- main loop: i-tiles 0..14 (staging next tile), phases k = itile*9+kpos ----
    for (int itile = 0; itile < 15; ++itile) {
#pragma unroll
        for (int kpos = 0; kpos < 9; ++kpos) {
            if (kpos < 8) STAGE_SLICE(itile + 1, kpos);
            {   // issue DMA for phase k+2
                int kN = (kpos + 2) % 9;
                int iN = itile + (kpos + 2) / 9;
                ISSUE_A(kN, iN, (kpos + 2) % 3);
            }
            COMPUTE(kpos, kpos % 3);
            if (kpos == 8) {
                asm volatile("s_waitcnt vmcnt(4)" ::: "memory");
                __builtin_amdgcn_s_barrier();
                WRITE_B();
                asm volatile("s_waitcnt lgkmcnt(0)" ::: "memory");
                __builtin_amdgcn_s_barrier();
            } else {
                asm volatile("s_waitcnt vmcnt(4)" ::: "memory");
                __builtin_amdgcn_s_barrier();
            }
        }
    }

    // ---- peeled i-tile 15: no B staging; tail vmcnt ----
#pragma unroll
    for (int kpos = 0; kpos < 9; ++kpos) {
        if (kpos <= 6) {
            int kN = (kpos + 2) % 9;
            ISSUE_A(kN, 15, (kpos + 2) % 3);
        }
        COMPUTE(kpos, kpos % 3);
        if (kpos < 7) {
            asm volatile("s_waitcnt vmcnt(4)" ::: "memory");
            __builtin_amdgcn_s_barrier();
        } else if (kpos == 7) {
            asm volatile("s_waitcnt vmcnt(0)" ::: "memory");
            __builtin_amdgcn_s_barrier();
        }
    }

    // ---- epilogue: scale by WMC * d[b,o], store fp32 ----
    size_t outb = (size_t)b * 512 * NP;
#pragma unroll
    for (int m = 0; m < 8; ++m) {
#pragma unroll
        for (int r = 0; r < 4; ++r) {
            int o_l = wr * 128 + m * 16 + q * 4 + r;
            float scale = W_MUL_CONV * s_d[o_l];
            size_t rb = outb + (size_t)(oB + o_l) * NP + strip * 124 + wc * OW;
#pragma unroll
            for (int n = 0; n < 4; ++n) {
                int col = n * 16 + frc;
                if (col < OW) out[rb + col] = acc[m][n][r] * scale;
            }
        }
    }
}

// ---------------- launch ----------------
extern "C" void kernel_launch(void* const* d_in, const int* in_sizes, int n_in,
                              void* d_out, int out_size, void* d_ws, size_t ws_size,
                              hipStream_t stream) {
    const float* x  = (const float*)d_in[0];   // [16,512,64,64]
    const float* y  = (const float*)d_in[1];   // [16,512]
    const float* dw = (const float*)d_in[2];   // [512,512]
    const float* db = (const float*)d_in[3];   // [512]
    const float* w  = (const float*)d_in[4];   // [512,512,3,3]
    float* out = (float*)d_out;                // [16,512,62,62]

    char* ws = (char*)d_ws;
    float* s_  = (float*)ws;                               // 16*512 f32   (32 KB)
    float* d_  = (float*)(ws + 32768);                     // 16*512 f32   (32 KB)
    float* wsq = (float*)(ws + 65536);                     // 512*512 f32  (1 MB)
    unsigned short* wb = (unsigned short*)(ws + 65536 + 1048576);  // 512*9*512 bf16 (4.72 MB)

    emc_style_kernel<<<32, 256, 0, stream>>>(y, dw, db, s_);
    emc_wsq_kernel<<<1024, 256, 0, stream>>>(w, wsq);
    emc_demod_kernel<<<32, 256, 0, stream>>>(s_, wsq, d_);
    emc_wrepack_kernel<<<9216, 256, 0, stream>>>(w, wb);
    emc_conv_kernel<<<16 * 62, 256, 0, stream>>>(x, wb, s_, d_, out);
}